// Round 1
// baseline (550.611 us; speedup 1.0000x reference)
//
#include <hip/hip_runtime.h>
#include <math.h>
#include <stdint.h>

#define ND_ROWS 16384
#define DDIM    256
#define KCODES  8192
#define NSEG    128        // 64-code segments
#define NRG     8          // row groups (XCD-affine), 2048 rows each

typedef _Float16 f16x4 __attribute__((ext_vector_type(4)));
typedef _Float16 f16x8 __attribute__((ext_vector_type(8)));
typedef float    f32x4v __attribute__((ext_vector_type(4)));
typedef float    f32x16 __attribute__((ext_vector_type(16)));

// ---------------------------------------------------------------------------
// ws layout (bytes):
//   minpair [0,        131072)   u64[16384]  (memset 0xFF each call)
//   counts  [131072,   163840)   int[8192]   (memset 0 each call)
//   parts   [163840,   196608)   de[4096] | dq[4096]
//   neF     [196608,   229376)   float[8192] = ||e||^2
//   Xp      [229376,   17006592) x as MFMA B-operand fragments, 16.8 MB:
//            per 32-row block rb (32 KB): hi q=0..15 then lo q=0..15; unit
//            (rb,q) = 1 KB; 16B chunk index within unit = (kg<<5)|rl holding
//            halves k = q*16 + kg*8 .. +8 of row rl. (coalesced 1KB/instr)
//   Bp      [17006592, 25395200) 8192 x 512 f16 = [-2e_hi(256) | -2e_lo(256)]
// ---------------------------------------------------------------------------

__device__ __attribute__((always_inline)) inline void load_lds16(const void* g, void* l) {
    __builtin_amdgcn_global_load_lds((const __attribute__((address_space(1))) void*)g,
                                     (__attribute__((address_space(3))) void*)l, 16, 0, 0);
}

// one wave per vector. x -> B-operand fragment layout (hi/lo split, unscaled).
// codebook -> row-major [-2e_hi | -2e_lo] (-2 folded in) + float ne table.
__global__ __launch_bounds__(256) void prep_kernel(const float* __restrict__ x,
                                                   const float* __restrict__ emb,
                                                   _Float16* __restrict__ Xp,
                                                   _Float16* __restrict__ Bp,
                                                   float* __restrict__ neF) {
    int wave = (blockIdx.x << 2) + (threadIdx.x >> 6);   // [0, 24576)
    int lane = threadIdx.x & 63;
    if (wave < ND_ROWS) {
        const float* src = x + (size_t)wave * DDIM;
        float4 v = ((const float4*)src)[lane];           // k = lane*4 .. +4
        f16x4 hi, lo;
        hi[0] = (_Float16)v.x; lo[0] = (_Float16)(v.x - (float)hi[0]);
        hi[1] = (_Float16)v.y; lo[1] = (_Float16)(v.y - (float)hi[1]);
        hi[2] = (_Float16)v.z; lo[2] = (_Float16)(v.z - (float)hi[2]);
        hi[3] = (_Float16)v.w; lo[3] = (_Float16)(v.w - (float)hi[3]);
        int rb = wave >> 5, rl = wave & 31;
        // q = lane>>2, kg = (lane>>1)&1, j0 = (lane&1)*4  (f16-unit offsets)
        size_t off = (size_t)rb * 16384 + ((lane >> 2) << 9)
                   + (((lane >> 1) & 1) << 8) + (rl << 3) + ((lane & 1) << 2);
        *(f16x4*)(Xp + off)        = hi;
        *(f16x4*)(Xp + off + 8192) = lo;                 // lo block: +16 KB
    } else {
        int r = wave - ND_ROWS;
        const float* src = emb + (size_t)r * DDIM;
        float4 v = ((const float4*)src)[lane];
        float s = v.x*v.x + v.y*v.y + v.z*v.z + v.w*v.w;  // ||e||^2 of original e
        #pragma unroll
        for (int m = 32; m; m >>= 1) s += __shfl_xor(s, m, 64);
        float4 t;                                         // fold the -2 in
        t.x = -2.0f * v.x; t.y = -2.0f * v.y; t.z = -2.0f * v.z; t.w = -2.0f * v.w;
        f16x4 hi, lo;
        hi[0] = (_Float16)t.x; lo[0] = (_Float16)(t.x - (float)hi[0]);
        hi[1] = (_Float16)t.y; lo[1] = (_Float16)(t.y - (float)hi[1]);
        hi[2] = (_Float16)t.z; lo[2] = (_Float16)(t.z - (float)hi[2]);
        hi[3] = (_Float16)t.w; lo[3] = (_Float16)(t.w - (float)hi[3]);
        _Float16* dst = Bp + (size_t)r * 512;
        *(f16x4*)(dst + lane * 4)       = hi;
        *(f16x4*)(dst + 256 + lane * 4) = lo;
        if (lane == 0) neF[r] = s;
    }
}

// Barrier-free argmin GEMM, codes-as-M, mfma_f32_32x32x16_f16.
// R12 restructure: 4-chunk accumulation (acc[4][2], 128 AGPR) + explicit
// 2-stage register pipeline (stage B = q+1 fragments loaded BEFORE stage A's
// 24-MFMA cluster -> compiler emits counted vmcnt(8)/lgkmcnt(4), loads stay
// in flight across the MFMA block) + s_setprio(1) around MFMA clusters.
// Rationale: R11 counters showed MfmaUtil 45% == exactly the MFMA-cycle
// floor / elapsed: per-wave MFMA duty ~11%, waves stalled on just-in-time
// L2 Xp loads in a too-short 12-MFMA body. 24-MFMA blocks (768 SIMD-cyc)
// exceed the L2 round-trip; each LDS code read now feeds 4 MFMAs (LDS instr
// count halves). Cost: ~250 regs/wave -> 8 waves/CU (2/SIMD, m201 precedent).
#define MFMA16(A, B, C) __builtin_amdgcn_mfma_f32_32x32x16_f16(A, B, C, 0, 0, 0)

#define DECL_STAGE(P) f16x8 P##xh0, P##xh1, P##xh2, P##xh3, \
                            P##xl0, P##xl1, P##xl2, P##xl3, \
                            P##c0, P##c1, P##d0, P##d1;

// x fragments: 4 chunks x (hi,lo). chunk c at xb + c*32768; lo at +16384.
#define LOADX(P, qq) { \
    P##xh0 = *(const f16x8*)(xb + (qq) * 1024); \
    P##xl0 = *(const f16x8*)(xb + 16384 + (qq) * 1024); \
    P##xh1 = *(const f16x8*)(xb + 32768 + (qq) * 1024); \
    P##xl1 = *(const f16x8*)(xb + 32768 + 16384 + (qq) * 1024); \
    P##xh2 = *(const f16x8*)(xb + 65536 + (qq) * 1024); \
    P##xl2 = *(const f16x8*)(xb + 65536 + 16384 + (qq) * 1024); \
    P##xh3 = *(const f16x8*)(xb + 98304 + (qq) * 1024); \
    P##xl3 = *(const f16x8*)(xb + 98304 + 16384 + (qq) * 1024); }

// code fragments: rows (c32, 32+c32), XOR bank swizzle by (c32&7).
// (32 + t) ^ s == 32 + (t ^ s) for t<32, s<8.
#define LOADC(P, qq) { \
    const int ph_ = (((qq) * 2 + kg) ^ sw); \
    const int pl_ = ((32 + (qq) * 2 + kg) ^ sw); \
    P##c0 = *(const f16x8*)(cp0 + ph_ * 16); \
    P##c1 = *(const f16x8*)(cp1 + ph_ * 16); \
    P##d0 = *(const f16x8*)(cp0 + pl_ * 16); \
    P##d1 = *(const f16x8*)(cp1 + pl_ * 16); }

// 24 MFMAs: 8 independent chains (acc[ck][mt]), round-robin so each chain's
// dependent issues are 8 slots apart.
#define MFMAS(P) \
    __builtin_amdgcn_s_setprio(1); \
    acc[0][0] = MFMA16(P##c0, P##xh0, acc[0][0]); \
    acc[0][1] = MFMA16(P##c1, P##xh0, acc[0][1]); \
    acc[1][0] = MFMA16(P##c0, P##xh1, acc[1][0]); \
    acc[1][1] = MFMA16(P##c1, P##xh1, acc[1][1]); \
    acc[2][0] = MFMA16(P##c0, P##xh2, acc[2][0]); \
    acc[2][1] = MFMA16(P##c1, P##xh2, acc[2][1]); \
    acc[3][0] = MFMA16(P##c0, P##xh3, acc[3][0]); \
    acc[3][1] = MFMA16(P##c1, P##xh3, acc[3][1]); \
    acc[0][0] = MFMA16(P##c0, P##xl0, acc[0][0]); \
    acc[0][1] = MFMA16(P##c1, P##xl0, acc[0][1]); \
    acc[1][0] = MFMA16(P##c0, P##xl1, acc[1][0]); \
    acc[1][1] = MFMA16(P##c1, P##xl1, acc[1][1]); \
    acc[2][0] = MFMA16(P##c0, P##xl2, acc[2][0]); \
    acc[2][1] = MFMA16(P##c1, P##xl2, acc[2][1]); \
    acc[3][0] = MFMA16(P##c0, P##xl3, acc[3][0]); \
    acc[3][1] = MFMA16(P##c1, P##xl3, acc[3][1]); \
    acc[0][0] = MFMA16(P##d0, P##xh0, acc[0][0]); \
    acc[0][1] = MFMA16(P##d1, P##xh0, acc[0][1]); \
    acc[1][0] = MFMA16(P##d0, P##xh1, acc[1][0]); \
    acc[1][1] = MFMA16(P##d1, P##xh1, acc[1][1]); \
    acc[2][0] = MFMA16(P##d0, P##xh2, acc[2][0]); \
    acc[2][1] = MFMA16(P##d1, P##xh2, acc[2][1]); \
    acc[3][0] = MFMA16(P##d0, P##xh3, acc[3][0]); \
    acc[3][1] = MFMA16(P##d1, P##xh3, acc[3][1]); \
    __builtin_amdgcn_s_setprio(0);

__global__ __launch_bounds__(512, 2) void argmin_seg(
    const _Float16* __restrict__ Xp, const _Float16* __restrict__ Bp,
    const float* __restrict__ neF, unsigned long long* __restrict__ minpair) {
    __shared__ __align__(16) _Float16 Cs[64 * 512];   // 64 KB, nothing else

    const int tid  = threadIdx.x;
    const int lane = tid & 63;
    const int w    = tid >> 6;     // 0..7
    const int c32  = lane & 31;
    const int kg   = lane >> 5;
    const int sw   = c32 & 7;

    const int rg      = blockIdx.x & 7;
    const int seg     = blockIdx.x >> 3;
    const int rowBase = rg * 2048;
    const int code0   = seg * 64;

    // stage code slab: wave w -> codes [w*8, w*8+8); per instr lane l is phys
    // 16B slot l, fetching logical chunk l ^ (code&7) (XOR bank swizzle).
    #pragma unroll
    for (int i = 0; i < 8; ++i) {
        int cl = w * 8 + i;
        int g  = lane ^ (cl & 7);
        load_lds16((const char*)(Bp + (size_t)(code0 + cl) * 512) + g * 16,
                   (char*)Cs + cl * 1024);
    }
    __syncthreads();   // the only barrier

    const char* cp0 = (const char*)Cs + c32 * 1024;
    const char* cp1 = cp0 + 32768;

    const int wBase = rowBase + w * 256;   // 2 groups of 4 chunks (128 rows)
    #pragma unroll 1
    for (int grp = 0; grp < 2; ++grp) {
        const int rb0 = (wBase >> 5) + grp * 4;
        const char* xb = (const char*)Xp + (size_t)rb0 * 32768 + lane * 16;

        f32x16 acc[4][2];   // [chunk][mt] - 8 independent chains, 128 AGPR
        #pragma unroll
        for (int ck = 0; ck < 4; ++ck) {
            #pragma unroll
            for (int i = 0; i < 16; ++i) { acc[ck][0][i] = 0.0f; acc[ck][1][i] = 0.0f; }
        }

        DECL_STAGE(a)
        DECL_STAGE(b)
        LOADX(a, 0)
        LOADC(a, 0)
        #pragma unroll
        for (int q = 0; q < 16; q += 2) {
            LOADX(b, q + 1)
            LOADC(b, q + 1)
            MFMAS(a)
            if (q + 2 < 16) {
                LOADX(a, q + 2)
                LOADC(a, q + 2)
            }
            MFMAS(b)
        }

        // epilogue: ne loaded here only (L1-hot after first use). Code id of
        // acc[ck][mt][r] = code0 + mt*32 + 4*kg + (r&3) + 8*(r>>2); (mt,r)
        // ascending <=> id ascending; strict < => first(lowest-index)-wins.
        f32x4v ne4[2][4];
        #pragma unroll
        for (int mt = 0; mt < 2; ++mt)
            #pragma unroll
            for (int g2 = 0; g2 < 4; ++g2)
                ne4[mt][g2] = *(const f32x4v*)(neF + code0 + mt * 32 + g2 * 8 + 4 * kg);
        #pragma unroll
        for (int ck = 0; ck < 4; ++ck) {
            float best = 3.402823466e+38f;
            int   bi   = 0;
            #pragma unroll
            for (int mt = 0; mt < 2; ++mt)
                #pragma unroll
                for (int r = 0; r < 16; ++r) {
                    float d  = acc[ck][mt][r] + ne4[mt][r >> 2][r & 3];
                    int   id = code0 + mt * 32 + 4 * kg + ((r & 3) + 8 * (r >> 2));
                    if (d < best) { best = d; bi = id; }
                }
            float ov = __shfl_xor(best, 32, 64);
            int   oi = __shfl_xor(bi, 32, 64);
            if (ov < best || (ov == best && oi < bi)) { best = ov; bi = oi; }
            if (kg == 0) {
                int row = (rb0 + ck) * 32 + c32;
                unsigned u = __float_as_uint(best);
                u = (u & 0x80000000u) ? ~u : (u | 0x80000000u);   // total-order map
                atomicMin(&minpair[row],
                          (((unsigned long long)u) << 32) | (unsigned)bi);
            }
        }
    }
}

// decode packed min, gather codebook row, write quantized_sg + float index,
// histogram atomic + per-block SSE partials.
__global__ __launch_bounds__(256) void finalize_kernel(
    const float* __restrict__ x, const float* __restrict__ emb,
    const unsigned long long* __restrict__ minpair,
    float* __restrict__ out_q, float* __restrict__ out_idx,
    int* __restrict__ counts, float* __restrict__ parts) {
    __shared__ float rde[4], rdq[4];
    int wv   = threadIdx.x >> 6;
    int row  = (blockIdx.x << 2) + wv;
    int lane = threadIdx.x & 63;

    int bi = (int)(minpair[row] & 0xFFFFFFFFull);

    float4 xv = ((const float4*)(x   + (size_t)row * DDIM))[lane];
    float4 ev = ((const float4*)(emb + (size_t)bi  * DDIM))[lane];
    float4 q;
    q.x = xv.x + (ev.x - xv.x);
    q.y = xv.y + (ev.y - xv.y);
    q.z = xv.z + (ev.z - xv.z);
    q.w = xv.w + (ev.w - xv.w);
    ((float4*)(out_q + (size_t)row * DDIM))[lane] = q;

    float de = (ev.x - xv.x) * (ev.x - xv.x) + (ev.y - xv.y) * (ev.y - xv.y)
             + (ev.z - xv.z) * (ev.z - xv.z) + (ev.w - xv.w) * (ev.w - xv.w);
    float dq = (q.x - ev.x) * (q.x - ev.x) + (q.y - ev.y) * (q.y - ev.y)
             + (q.z - ev.z) * (q.z - ev.z) + (q.w - ev.w) * (q.w - ev.w);
    #pragma unroll
    for (int m = 32; m; m >>= 1) {
        de += __shfl_xor(de, m, 64);
        dq += __shfl_xor(dq, m, 64);
    }
    if (lane == 0) {
        out_idx[row] = (float)bi;
        atomicAdd(&counts[bi], 1);
        rde[wv] = de; rdq[wv] = dq;
    }
    __syncthreads();
    if (threadIdx.x == 0) {
        parts[blockIdx.x]        = rde[0] + rde[1] + rde[2] + rde[3];
        parts[4096 + blockIdx.x] = rdq[0] + rdq[1] + rdq[2] + rdq[3];
    }
}

__global__ __launch_bounds__(256) void scalars_kernel(
    const int* __restrict__ counts, const float* __restrict__ parts,
    float* __restrict__ out_loss, float* __restrict__ out_perp) {
    __shared__ float red[256], rde[256], rdq[256];
    float local = 0.0f, de = 0.0f, dq = 0.0f;
    for (int k = threadIdx.x; k < KCODES; k += 256) {
        float p = (float)counts[k] * (1.0f / (float)ND_ROWS);
        local += p * logf(p + 1e-10f);
    }
    for (int k = threadIdx.x; k < 4096; k += 256) {
        de += parts[k];
        dq += parts[4096 + k];
    }
    red[threadIdx.x] = local; rde[threadIdx.x] = de; rdq[threadIdx.x] = dq;
    __syncthreads();
    for (int s = 128; s; s >>= 1) {
        if (threadIdx.x < s) {
            red[threadIdx.x] += red[threadIdx.x + s];
            rde[threadIdx.x] += rde[threadIdx.x + s];
            rdq[threadIdx.x] += rdq[threadIdx.x + s];
        }
        __syncthreads();
    }
    if (threadIdx.x == 0) {
        *out_perp = expf(-red[0]);
        float invn = 1.0f / (float)(ND_ROWS * DDIM);
        *out_loss = rdq[0] * invn + 0.25f * (rde[0] * invn);
    }
}

extern "C" void kernel_launch(void* const* d_in, const int* in_sizes, int n_in,
                              void* d_out, int out_size, void* d_ws, size_t ws_size,
                              hipStream_t stream) {
    const float* x   = (const float*)d_in[0];
    const float* emb = (const float*)d_in[1];

    char* ws = (char*)d_ws;
    unsigned long long* minpair = (unsigned long long*)ws;         // 128 KB
    int*      counts = (int*)(ws + 131072);                        // 32 KB
    float*    parts  = (float*)(ws + 163840);                      // 32 KB
    float*    neF    = (float*)(ws + 196608);                      // 32 KB
    _Float16* Xp     = (_Float16*)(ws + 229376);                   // 16.8 MB
    _Float16* Bp     = (_Float16*)(ws + 17006592);                 // 8.4 MB

    float* out_q    = (float*)d_out;
    float* out_idx  = out_q + (size_t)ND_ROWS * DDIM;
    float* out_loss = out_idx + ND_ROWS;
    float* out_perp = out_loss + 1;

    hipMemsetAsync(minpair, 0xFF, ND_ROWS * sizeof(unsigned long long), stream);
    hipMemsetAsync(counts, 0, KCODES * sizeof(int), stream);

    prep_kernel<<<(KCODES + ND_ROWS) / 4, 256, 0, stream>>>(x, emb, Xp, Bp, neF);
    argmin_seg<<<NRG * NSEG, 512, 0, stream>>>(Xp, Bp, neF, minpair);
    finalize_kernel<<<ND_ROWS / 4, 256, 0, stream>>>(x, emb, minpair,
                                                     out_q, out_idx, counts, parts);
    scalars_kernel<<<1, 256, 0, stream>>>(counts, parts, out_loss, out_perp);
}

// Round 2
// 456.212 us; speedup vs baseline: 1.2069x; 1.2069x over previous
//
#include <hip/hip_runtime.h>
#include <math.h>
#include <stdint.h>

#define ND_ROWS 16384
#define DDIM    256
#define KCODES  8192
#define NSEG    128        // 64-code segments
#define NRG     8          // row groups (XCD-affine), 2048 rows each

typedef _Float16 f16x4 __attribute__((ext_vector_type(4)));
typedef _Float16 f16x8 __attribute__((ext_vector_type(8)));
typedef float    f32x4v __attribute__((ext_vector_type(4)));
typedef float    f32x16 __attribute__((ext_vector_type(16)));

// ---------------------------------------------------------------------------
// ws layout (bytes):
//   minpair [0,        131072)   u64[16384]  (memset 0xFF each call)
//   counts  [131072,   163840)   int[8192]   (memset 0 each call)
//   parts   [163840,   196608)   de[4096] | dq[4096]
//   neF     [196608,   229376)   float[8192] = ||e||^2
//   Xp      [229376,   17006592) x as MFMA B-operand fragments, 16.8 MB:
//            per 32-row block rb (32 KB): hi q=0..15 then lo q=0..15; unit
//            (rb,q) = 1 KB; 16B chunk index within unit = (kg<<5)|rl holding
//            halves k = q*16 + kg*8 .. +8 of row rl. (coalesced 1KB/instr)
//   Bp      [17006592, 25395200) 8192 x 512 f16 = [-2e_hi(256) | -2e_lo(256)]
// ---------------------------------------------------------------------------

__device__ __attribute__((always_inline)) inline void load_lds16(const void* g, void* l) {
    __builtin_amdgcn_global_load_lds((const __attribute__((address_space(1))) void*)g,
                                     (__attribute__((address_space(3))) void*)l, 16, 0, 0);
}

// one wave per vector. x -> B-operand fragment layout (hi/lo split, unscaled).
// codebook -> row-major [-2e_hi | -2e_lo] (-2 folded in) + float ne table.
__global__ __launch_bounds__(256) void prep_kernel(const float* __restrict__ x,
                                                   const float* __restrict__ emb,
                                                   _Float16* __restrict__ Xp,
                                                   _Float16* __restrict__ Bp,
                                                   float* __restrict__ neF) {
    int wave = (blockIdx.x << 2) + (threadIdx.x >> 6);   // [0, 24576)
    int lane = threadIdx.x & 63;
    if (wave < ND_ROWS) {
        const float* src = x + (size_t)wave * DDIM;
        float4 v = ((const float4*)src)[lane];           // k = lane*4 .. +4
        f16x4 hi, lo;
        hi[0] = (_Float16)v.x; lo[0] = (_Float16)(v.x - (float)hi[0]);
        hi[1] = (_Float16)v.y; lo[1] = (_Float16)(v.y - (float)hi[1]);
        hi[2] = (_Float16)v.z; lo[2] = (_Float16)(v.z - (float)hi[2]);
        hi[3] = (_Float16)v.w; lo[3] = (_Float16)(v.w - (float)hi[3]);
        int rb = wave >> 5, rl = wave & 31;
        // q = lane>>2, kg = (lane>>1)&1, j0 = (lane&1)*4  (f16-unit offsets)
        size_t off = (size_t)rb * 16384 + ((lane >> 2) << 9)
                   + (((lane >> 1) & 1) << 8) + (rl << 3) + ((lane & 1) << 2);
        *(f16x4*)(Xp + off)        = hi;
        *(f16x4*)(Xp + off + 8192) = lo;                 // lo block: +16 KB
    } else {
        int r = wave - ND_ROWS;
        const float* src = emb + (size_t)r * DDIM;
        float4 v = ((const float4*)src)[lane];
        float s = v.x*v.x + v.y*v.y + v.z*v.z + v.w*v.w;  // ||e||^2 of original e
        #pragma unroll
        for (int m = 32; m; m >>= 1) s += __shfl_xor(s, m, 64);
        float4 t;                                         // fold the -2 in
        t.x = -2.0f * v.x; t.y = -2.0f * v.y; t.z = -2.0f * v.z; t.w = -2.0f * v.w;
        f16x4 hi, lo;
        hi[0] = (_Float16)t.x; lo[0] = (_Float16)(t.x - (float)hi[0]);
        hi[1] = (_Float16)t.y; lo[1] = (_Float16)(t.y - (float)hi[1]);
        hi[2] = (_Float16)t.z; lo[2] = (_Float16)(t.z - (float)hi[2]);
        hi[3] = (_Float16)t.w; lo[3] = (_Float16)(t.w - (float)hi[3]);
        _Float16* dst = Bp + (size_t)r * 512;
        *(f16x4*)(dst + lane * 4)       = hi;
        *(f16x4*)(dst + 256 + lane * 4) = lo;
        if (lane == 0) neF[r] = s;
    }
}

// Barrier-free argmin GEMM, codes-as-M, mfma_f32_32x32x16_f16, 2-chunk blocked.
// R13: R11's proven acc[2][2] math + explicit 2-stage register double-buffer.
// Post-mortem R12: acc[4][2]+pipeline = ~280 regs > 256 cap -> spilled
// (WRITE_SIZE 42->653 MB). Post-mortem R11: VGPR 64 + AGPR 64 = exactly 128
// unified regs (the 4-wave/SIMD boundary) -> compiler had ZERO regs for
// prefetch -> just-in-time loads -> per-wave MFMA duty ~14%, MfmaUtil 45%.
// Fix: budget ~160 of 256 regs (launch_bounds(512,2)): 64 acc + 64 stage
// (2 x 8 f16x8) + addr. Loads for step q+1 issue a full 384-cy MFMA cluster
// ahead of use (> L2 ~200cy, > LDS ~120cy). 2 waves/SIMD, barrier-free so
// waves drift phase; setprio(1) biases MFMA-issuing wave (T5).
#define MFMA16(A, B, C) __builtin_amdgcn_mfma_f32_32x32x16_f16(A, B, C, 0, 0, 0)

#define DECL_STAGE(P) f16x8 P##xh0, P##xl0, P##xh1, P##xl1, \
                            P##c0, P##c1, P##d0, P##d1;

// x fragments: 2 chunks x (hi,lo). chunk 1 at xb0 + 32768; lo at +16384.
#define LOADX(P, qq) { \
    P##xh0 = *(const f16x8*)(xb0 + (qq) * 1024); \
    P##xl0 = *(const f16x8*)(xb0 + 16384 + (qq) * 1024); \
    P##xh1 = *(const f16x8*)(xb1 + (qq) * 1024); \
    P##xl1 = *(const f16x8*)(xb1 + 16384 + (qq) * 1024); }

// code fragments: rows (c32, 32+c32), XOR bank swizzle by (c32&7).
// (32 + t) ^ s == 32 + (t ^ s) for t<32, s<8.
#define LOADC(P, qq) { \
    const int ph_ = (((qq) * 2 + kg) ^ sw); \
    const int pl_ = ((32 + (qq) * 2 + kg) ^ sw); \
    P##c0 = *(const f16x8*)(cp0 + ph_ * 16); \
    P##c1 = *(const f16x8*)(cp1 + ph_ * 16); \
    P##d0 = *(const f16x8*)(cp0 + pl_ * 16); \
    P##d1 = *(const f16x8*)(cp1 + pl_ * 16); }

// 12 MFMAs: 4 independent chains (acc[ck][mt]), round-robin so each chain's
// dependent issues are 4 slots (128 issue-cycles) apart.
#define MFMAS(P) \
    __builtin_amdgcn_s_setprio(1); \
    acc[0][0] = MFMA16(P##c0, P##xh0, acc[0][0]); \
    acc[0][1] = MFMA16(P##c1, P##xh0, acc[0][1]); \
    acc[1][0] = MFMA16(P##c0, P##xh1, acc[1][0]); \
    acc[1][1] = MFMA16(P##c1, P##xh1, acc[1][1]); \
    acc[0][0] = MFMA16(P##c0, P##xl0, acc[0][0]); \
    acc[0][1] = MFMA16(P##c1, P##xl0, acc[0][1]); \
    acc[1][0] = MFMA16(P##c0, P##xl1, acc[1][0]); \
    acc[1][1] = MFMA16(P##c1, P##xl1, acc[1][1]); \
    acc[0][0] = MFMA16(P##d0, P##xh0, acc[0][0]); \
    acc[0][1] = MFMA16(P##d1, P##xh0, acc[0][1]); \
    acc[1][0] = MFMA16(P##d0, P##xh1, acc[1][0]); \
    acc[1][1] = MFMA16(P##d1, P##xh1, acc[1][1]); \
    __builtin_amdgcn_s_setprio(0);

__global__ __launch_bounds__(512, 2) void argmin_seg(
    const _Float16* __restrict__ Xp, const _Float16* __restrict__ Bp,
    const float* __restrict__ neF, unsigned long long* __restrict__ minpair) {
    __shared__ __align__(16) _Float16 Cs[64 * 512];   // 64 KB, nothing else

    const int tid  = threadIdx.x;
    const int lane = tid & 63;
    const int w    = tid >> 6;     // 0..7
    const int c32  = lane & 31;
    const int kg   = lane >> 5;
    const int sw   = c32 & 7;

    const int rg      = blockIdx.x & 7;
    const int seg     = blockIdx.x >> 3;
    const int rowBase = rg * 2048;
    const int code0   = seg * 64;

    // stage code slab: wave w -> codes [w*8, w*8+8); per instr lane l is phys
    // 16B slot l, fetching logical chunk l ^ (code&7) (XOR bank swizzle).
    #pragma unroll
    for (int i = 0; i < 8; ++i) {
        int cl = w * 8 + i;
        int g  = lane ^ (cl & 7);
        load_lds16((const char*)(Bp + (size_t)(code0 + cl) * 512) + g * 16,
                   (char*)Cs + cl * 1024);
    }
    __syncthreads();   // the only barrier

    const char* cp0 = (const char*)Cs + c32 * 1024;
    const char* cp1 = cp0 + 32768;

    const int wBase = rowBase + w * 256;   // 4 chunk-pairs of 64 rows per wave
    #pragma unroll 1
    for (int c2 = 0; c2 < 4; ++c2) {
        const int rb0 = (wBase >> 5) + c2 * 2;
        const char* xb0 = (const char*)Xp + (size_t)rb0 * 32768 + lane * 16;
        const char* xb1 = xb0 + 32768;

        f32x16 acc[2][2];   // [chunk][mt] - 4 independent chains, 64 AGPR
        #pragma unroll
        for (int i = 0; i < 16; ++i) {
            acc[0][0][i] = 0.0f; acc[0][1][i] = 0.0f;
            acc[1][0][i] = 0.0f; acc[1][1][i] = 0.0f;
        }

        DECL_STAGE(a)
        DECL_STAGE(b)
        LOADX(a, 0)
        LOADC(a, 0)
        #pragma unroll
        for (int q = 0; q < 16; q += 2) {
            LOADX(b, q + 1)
            LOADC(b, q + 1)
            MFMAS(a)
            if (q + 2 < 16) {
                LOADX(a, q + 2)
                LOADC(a, q + 2)
            }
            MFMAS(b)
        }

        // epilogue: ne loaded here only (L1-hot after first iter). Code id of
        // acc[ck][mt][r] = code0 + mt*32 + 4*kg + (r&3) + 8*(r>>2); (mt,r)
        // ascending <=> id ascending; strict < => first(lowest-index)-wins.
        f32x4v ne4[2][4];
        #pragma unroll
        for (int mt = 0; mt < 2; ++mt)
            #pragma unroll
            for (int g2 = 0; g2 < 4; ++g2)
                ne4[mt][g2] = *(const f32x4v*)(neF + code0 + mt * 32 + g2 * 8 + 4 * kg);
        #pragma unroll
        for (int ck = 0; ck < 2; ++ck) {
            float best = 3.402823466e+38f;
            int   bi   = 0;
            #pragma unroll
            for (int mt = 0; mt < 2; ++mt)
                #pragma unroll
                for (int r = 0; r < 16; ++r) {
                    float d  = acc[ck][mt][r] + ne4[mt][r >> 2][r & 3];
                    int   id = code0 + mt * 32 + 4 * kg + ((r & 3) + 8 * (r >> 2));
                    if (d < best) { best = d; bi = id; }
                }
            float ov = __shfl_xor(best, 32, 64);
            int   oi = __shfl_xor(bi, 32, 64);
            if (ov < best || (ov == best && oi < bi)) { best = ov; bi = oi; }
            if (kg == 0) {
                int row = (rb0 + ck) * 32 + c32;
                unsigned u = __float_as_uint(best);
                u = (u & 0x80000000u) ? ~u : (u | 0x80000000u);   // total-order map
                atomicMin(&minpair[row],
                          (((unsigned long long)u) << 32) | (unsigned)bi);
            }
        }
    }
}

// decode packed min, gather codebook row, write quantized_sg + float index,
// histogram atomic + per-block SSE partials.
__global__ __launch_bounds__(256) void finalize_kernel(
    const float* __restrict__ x, const float* __restrict__ emb,
    const unsigned long long* __restrict__ minpair,
    float* __restrict__ out_q, float* __restrict__ out_idx,
    int* __restrict__ counts, float* __restrict__ parts) {
    __shared__ float rde[4], rdq[4];
    int wv   = threadIdx.x >> 6;
    int row  = (blockIdx.x << 2) + wv;
    int lane = threadIdx.x & 63;

    int bi = (int)(minpair[row] & 0xFFFFFFFFull);

    float4 xv = ((const float4*)(x   + (size_t)row * DDIM))[lane];
    float4 ev = ((const float4*)(emb + (size_t)bi  * DDIM))[lane];
    float4 q;
    q.x = xv.x + (ev.x - xv.x);
    q.y = xv.y + (ev.y - xv.y);
    q.z = xv.z + (ev.z - xv.z);
    q.w = xv.w + (ev.w - xv.w);
    ((float4*)(out_q + (size_t)row * DDIM))[lane] = q;

    float de = (ev.x - xv.x) * (ev.x - xv.x) + (ev.y - xv.y) * (ev.y - xv.y)
             + (ev.z - xv.z) * (ev.z - xv.z) + (ev.w - xv.w) * (ev.w - xv.w);
    float dq = (q.x - ev.x) * (q.x - ev.x) + (q.y - ev.y) * (q.y - ev.y)
             + (q.z - ev.z) * (q.z - ev.z) + (q.w - ev.w) * (q.w - ev.w);
    #pragma unroll
    for (int m = 32; m; m >>= 1) {
        de += __shfl_xor(de, m, 64);
        dq += __shfl_xor(dq, m, 64);
    }
    if (lane == 0) {
        out_idx[row] = (float)bi;
        atomicAdd(&counts[bi], 1);
        rde[wv] = de; rdq[wv] = dq;
    }
    __syncthreads();
    if (threadIdx.x == 0) {
        parts[blockIdx.x]        = rde[0] + rde[1] + rde[2] + rde[3];
        parts[4096 + blockIdx.x] = rdq[0] + rdq[1] + rdq[2] + rdq[3];
    }
}

__global__ __launch_bounds__(256) void scalars_kernel(
    const int* __restrict__ counts, const float* __restrict__ parts,
    float* __restrict__ out_loss, float* __restrict__ out_perp) {
    __shared__ float red[256], rde[256], rdq[256];
    float local = 0.0f, de = 0.0f, dq = 0.0f;
    for (int k = threadIdx.x; k < KCODES; k += 256) {
        float p = (float)counts[k] * (1.0f / (float)ND_ROWS);
        local += p * logf(p + 1e-10f);
    }
    for (int k = threadIdx.x; k < 4096; k += 256) {
        de += parts[k];
        dq += parts[4096 + k];
    }
    red[threadIdx.x] = local; rde[threadIdx.x] = de; rdq[threadIdx.x] = dq;
    __syncthreads();
    for (int s = 128; s; s >>= 1) {
        if (threadIdx.x < s) {
            red[threadIdx.x] += red[threadIdx.x + s];
            rde[threadIdx.x] += rde[threadIdx.x + s];
            rdq[threadIdx.x] += rdq[threadIdx.x + s];
        }
        __syncthreads();
    }
    if (threadIdx.x == 0) {
        *out_perp = expf(-red[0]);
        float invn = 1.0f / (float)(ND_ROWS * DDIM);
        *out_loss = rdq[0] * invn + 0.25f * (rde[0] * invn);
    }
}

extern "C" void kernel_launch(void* const* d_in, const int* in_sizes, int n_in,
                              void* d_out, int out_size, void* d_ws, size_t ws_size,
                              hipStream_t stream) {
    const float* x   = (const float*)d_in[0];
    const float* emb = (const float*)d_in[1];

    char* ws = (char*)d_ws;
    unsigned long long* minpair = (unsigned long long*)ws;         // 128 KB
    int*      counts = (int*)(ws + 131072);                        // 32 KB
    float*    parts  = (float*)(ws + 163840);                      // 32 KB
    float*    neF    = (float*)(ws + 196608);                      // 32 KB
    _Float16* Xp     = (_Float16*)(ws + 229376);                   // 16.8 MB
    _Float16* Bp     = (_Float16*)(ws + 17006592);                 // 8.4 MB

    float* out_q    = (float*)d_out;
    float* out_idx  = out_q + (size_t)ND_ROWS * DDIM;
    float* out_loss = out_idx + ND_ROWS;
    float* out_perp = out_loss + 1;

    hipMemsetAsync(minpair, 0xFF, ND_ROWS * sizeof(unsigned long long), stream);
    hipMemsetAsync(counts, 0, KCODES * sizeof(int), stream);

    prep_kernel<<<(KCODES + ND_ROWS) / 4, 256, 0, stream>>>(x, emb, Xp, Bp, neF);
    argmin_seg<<<NRG * NSEG, 512, 0, stream>>>(Xp, Bp, neF, minpair);
    finalize_kernel<<<ND_ROWS / 4, 256, 0, stream>>>(x, emb, minpair,
                                                     out_q, out_idx, counts, parts);
    scalars_kernel<<<1, 256, 0, stream>>>(counts, parts, out_loss, out_perp);
}

// Round 3
// 310.938 us; speedup vs baseline: 1.7708x; 1.4672x over previous
//
#include <hip/hip_runtime.h>
#include <math.h>
#include <stdint.h>

#define ND_ROWS 16384
#define DDIM    256
#define KCODES  8192
#define NSEG    128        // 64-code segments
#define NRG     8          // row groups (XCD-affine), 2048 rows each

typedef _Float16 f16x4 __attribute__((ext_vector_type(4)));
typedef _Float16 f16x8 __attribute__((ext_vector_type(8)));
typedef float    f32x4v __attribute__((ext_vector_type(4)));
typedef float    f32x16 __attribute__((ext_vector_type(16)));

// ---------------------------------------------------------------------------
// ws layout (bytes):
//   minpair [0,        131072)   u64[16384]  (memset 0xFF each call)
//   counts  [131072,   163840)   int[8192]   (memset 0 each call)
//   parts   [163840,   196608)   de[4096] | dq[4096]
//   neF     [196608,   229376)   float[8192] = ||e||^2
//   Xp      [229376,   17006592) x as MFMA B-operand fragments, 16.8 MB:
//            per 32-row block rb (32 KB): hi q=0..15 then lo q=0..15; unit
//            (rb,q) = 1 KB; 16B chunk index within unit = (kg<<5)|rl holding
//            halves k = q*16 + kg*8 .. +8 of row rl. (coalesced 1KB/instr)
//   Bp      [17006592, 25395200) 8192 x 512 f16 = [-2e_hi(256) | -2e_lo(256)]
// ---------------------------------------------------------------------------

__device__ __attribute__((always_inline)) inline void load_lds16(const void* g, void* l) {
    __builtin_amdgcn_global_load_lds((const __attribute__((address_space(1))) void*)g,
                                     (__attribute__((address_space(3))) void*)l, 16, 0, 0);
}

// one wave per vector. x -> B-operand fragment layout (hi/lo split, unscaled).
// codebook -> row-major [-2e_hi | -2e_lo] (-2 folded in) + float ne table.
__global__ __launch_bounds__(256) void prep_kernel(const float* __restrict__ x,
                                                   const float* __restrict__ emb,
                                                   _Float16* __restrict__ Xp,
                                                   _Float16* __restrict__ Bp,
                                                   float* __restrict__ neF) {
    int wave = (blockIdx.x << 2) + (threadIdx.x >> 6);   // [0, 24576)
    int lane = threadIdx.x & 63;
    if (wave < ND_ROWS) {
        const float* src = x + (size_t)wave * DDIM;
        float4 v = ((const float4*)src)[lane];           // k = lane*4 .. +4
        f16x4 hi, lo;
        hi[0] = (_Float16)v.x; lo[0] = (_Float16)(v.x - (float)hi[0]);
        hi[1] = (_Float16)v.y; lo[1] = (_Float16)(v.y - (float)hi[1]);
        hi[2] = (_Float16)v.z; lo[2] = (_Float16)(v.z - (float)hi[2]);
        hi[3] = (_Float16)v.w; lo[3] = (_Float16)(v.w - (float)hi[3]);
        int rb = wave >> 5, rl = wave & 31;
        // q = lane>>2, kg = (lane>>1)&1, j0 = (lane&1)*4  (f16-unit offsets)
        size_t off = (size_t)rb * 16384 + ((lane >> 2) << 9)
                   + (((lane >> 1) & 1) << 8) + (rl << 3) + ((lane & 1) << 2);
        *(f16x4*)(Xp + off)        = hi;
        *(f16x4*)(Xp + off + 8192) = lo;                 // lo block: +16 KB
    } else {
        int r = wave - ND_ROWS;
        const float* src = emb + (size_t)r * DDIM;
        float4 v = ((const float4*)src)[lane];
        float s = v.x*v.x + v.y*v.y + v.z*v.z + v.w*v.w;  // ||e||^2 of original e
        #pragma unroll
        for (int m = 32; m; m >>= 1) s += __shfl_xor(s, m, 64);
        float4 t;                                         // fold the -2 in
        t.x = -2.0f * v.x; t.y = -2.0f * v.y; t.z = -2.0f * v.z; t.w = -2.0f * v.w;
        f16x4 hi, lo;
        hi[0] = (_Float16)t.x; lo[0] = (_Float16)(t.x - (float)hi[0]);
        hi[1] = (_Float16)t.y; lo[1] = (_Float16)(t.y - (float)hi[1]);
        hi[2] = (_Float16)t.z; lo[2] = (_Float16)(t.z - (float)hi[2]);
        hi[3] = (_Float16)t.w; lo[3] = (_Float16)(t.w - (float)hi[3]);
        _Float16* dst = Bp + (size_t)r * 512;
        *(f16x4*)(dst + lane * 4)       = hi;
        *(f16x4*)(dst + 256 + lane * 4) = lo;
        if (lane == 0) neF[r] = s;
    }
}

// Barrier-free argmin GEMM, codes-as-M, mfma_f32_32x32x16_f16, 2-chunk blocked.
// R14 = R11's exact proven structure (acc[2][2], unroll 2, launch_bounds(512,4),
// no manual staging) + ONE change: transposed code-slab LDS layout.
//
// Post-mortems: R12/R13 explicit-staging both spilled (~350 MB scratch writes)
// because full unroll + named stage regs let the scheduler hoist across all 8
// bodies -> liveness >> cap. Reverted (Common-mistake #5).
//
// R11's 8.39M SQ_LDS_BANK_CONFLICT = 4 extra cyc per ds_read_b128: rows at
// 1 KB stride are bank-identical; XOR swizzle only spreads within c32&7
// groups; lanes {i,i+8,i+16,i+24} always share a 4-bank set.
// Fix: store the slab TRANSPOSED at 16B granule: per 32-code half,
//   phys = slot*512 + c32*16   (slot = the 8-half k-group index, 0..63).
// A wave's 4 ds_read_b128 per q are then each one contiguous 1 KB
// (kg=0 lanes -> first 512B, kg=1 -> next 512B) = canonical conflict-free
// pattern. Staging keeps LDS dest linear and pre-swizzles the per-lane
// GLOBAL source (global_load_lds src is per-lane; dest is base+lane*16).
// Bonus: XOR address math leaves the inner loop.
#define MFMA16(A, B, C) __builtin_amdgcn_mfma_f32_32x32x16_f16(A, B, C, 0, 0, 0)

__global__ __launch_bounds__(512, 4) void argmin_seg(
    const _Float16* __restrict__ Xp, const _Float16* __restrict__ Bp,
    const float* __restrict__ neF, unsigned long long* __restrict__ minpair) {
    __shared__ __align__(16) _Float16 Cs[64 * 512];   // 64 KB, nothing else

    const int tid  = threadIdx.x;
    const int lane = tid & 63;
    const int w    = tid >> 6;     // 0..7
    const int c32  = lane & 31;
    const int kg   = lane >> 5;

    const int rg      = blockIdx.x & 7;
    const int seg     = blockIdx.x >> 3;
    const int rowBase = rg * 2048;
    const int code0   = seg * 64;

    // stage code slab TRANSPOSED: LDS chunk j (1 KB, linear dest) holds
    // { slot 2*(j&31)+0 : codes 0..31 | slot 2*(j&31)+1 : codes 0..31 } of
    // code-half (j>>5). Lane l fetches global Bp[code0 + (j&32) + (l&31)]
    // slot (2*(j&31) + (l>>5)).  (16B-gather src; prologue-only, L2-hot.)
    #pragma unroll
    for (int i = 0; i < 8; ++i) {
        int j    = w * 8 + i;
        int code = code0 + (j & 32) + (lane & 31);
        int s    = ((j & 31) << 1) | (lane >> 5);
        load_lds16((const char*)Bp + ((size_t)code << 10) + (s << 4),
                   (char*)Cs + (j << 10));
    }
    __syncthreads();   // the only barrier

    // read base: lane offset c32*16 within a 512B slot-row, kg picks the
    // adjacent slot. Per q: 4 reads at compile-time offsets, each wave-
    // contiguous 1 KB -> conflict-free.
    //   ch0 = +q*1024            (codes  0..31, hi)
    //   cl0 = +16384 + q*1024    (codes  0..31, lo)
    //   ch1 = +32768 + q*1024    (codes 32..63, hi)
    //   cl1 = +49152 + q*1024    (codes 32..63, lo)
    const char* cpb = (const char*)Cs + (kg << 9) + (c32 << 4);

    const int wBase = rowBase + w * 256;   // 4 chunk-pairs of 64 rows per wave
    for (int c2 = 0; c2 < 4; ++c2) {
        const int rb0 = (wBase >> 5) + c2 * 2;
        const char* xb0 = (const char*)Xp + (size_t)rb0 * 32768 + lane * 16;
        const char* xb1 = xb0 + 32768;
        f32x16 acc[2][2];   // [chunk][mt] - 4 independent MFMA chains, 64 AGPR
        #pragma unroll
        for (int i = 0; i < 16; ++i) {
            acc[0][0][i] = 0.0f; acc[0][1][i] = 0.0f;
            acc[1][0][i] = 0.0f; acc[1][1][i] = 0.0f;
        }

        #pragma unroll 2
        for (int q = 0; q < 16; ++q) {
            f16x8 xh0 = *(const f16x8*)(xb0 + q * 1024);
            f16x8 xl0 = *(const f16x8*)(xb0 + 16384 + q * 1024);
            f16x8 xh1 = *(const f16x8*)(xb1 + q * 1024);
            f16x8 xl1 = *(const f16x8*)(xb1 + 16384 + q * 1024);
            f16x8 ch0 = *(const f16x8*)(cpb + q * 1024);
            f16x8 cl0 = *(const f16x8*)(cpb + 16384 + q * 1024);
            f16x8 ch1 = *(const f16x8*)(cpb + 32768 + q * 1024);
            f16x8 cl1 = *(const f16x8*)(cpb + 49152 + q * 1024);
            // 12 MFMAs, chain-interleaved (each chain's next issue is 4 slots away)
            acc[0][0] = MFMA16(ch0, xh0, acc[0][0]);
            acc[0][1] = MFMA16(ch1, xh0, acc[0][1]);
            acc[1][0] = MFMA16(ch0, xh1, acc[1][0]);
            acc[1][1] = MFMA16(ch1, xh1, acc[1][1]);
            acc[0][0] = MFMA16(ch0, xl0, acc[0][0]);
            acc[0][1] = MFMA16(ch1, xl0, acc[0][1]);
            acc[1][0] = MFMA16(ch0, xl1, acc[1][0]);
            acc[1][1] = MFMA16(ch1, xl1, acc[1][1]);
            acc[0][0] = MFMA16(cl0, xh0, acc[0][0]);
            acc[0][1] = MFMA16(cl1, xh0, acc[0][1]);
            acc[1][0] = MFMA16(cl0, xh1, acc[1][0]);
            acc[1][1] = MFMA16(cl1, xh1, acc[1][1]);
        }

        // epilogue: ne loaded here only (L1-hot after first iter). Code id of
        // acc[ck][mt][r] = code0 + mt*32 + 4*kg + (r&3) + 8*(r>>2); (mt,r)
        // ascending <=> id ascending; strict < => first(lowest-index)-wins.
        f32x4v ne4[2][4];
        #pragma unroll
        for (int mt = 0; mt < 2; ++mt)
            #pragma unroll
            for (int g2 = 0; g2 < 4; ++g2)
                ne4[mt][g2] = *(const f32x4v*)(neF + code0 + mt * 32 + g2 * 8 + 4 * kg);
        #pragma unroll
        for (int ck = 0; ck < 2; ++ck) {
            float best = 3.402823466e+38f;
            int   bi   = 0;
            #pragma unroll
            for (int mt = 0; mt < 2; ++mt)
                #pragma unroll
                for (int r = 0; r < 16; ++r) {
                    float d  = acc[ck][mt][r] + ne4[mt][r >> 2][r & 3];
                    int   id = code0 + mt * 32 + 4 * kg + ((r & 3) + 8 * (r >> 2));
                    if (d < best) { best = d; bi = id; }
                }
            float ov = __shfl_xor(best, 32, 64);
            int   oi = __shfl_xor(bi, 32, 64);
            if (ov < best || (ov == best && oi < bi)) { best = ov; bi = oi; }
            if (kg == 0) {
                int row = (rb0 + ck) * 32 + c32;
                unsigned u = __float_as_uint(best);
                u = (u & 0x80000000u) ? ~u : (u | 0x80000000u);   // total-order map
                atomicMin(&minpair[row],
                          (((unsigned long long)u) << 32) | (unsigned)bi);
            }
        }
    }
}

// decode packed min, gather codebook row, write quantized_sg + float index,
// histogram atomic + per-block SSE partials.
__global__ __launch_bounds__(256) void finalize_kernel(
    const float* __restrict__ x, const float* __restrict__ emb,
    const unsigned long long* __restrict__ minpair,
    float* __restrict__ out_q, float* __restrict__ out_idx,
    int* __restrict__ counts, float* __restrict__ parts) {
    __shared__ float rde[4], rdq[4];
    int wv   = threadIdx.x >> 6;
    int row  = (blockIdx.x << 2) + wv;
    int lane = threadIdx.x & 63;

    int bi = (int)(minpair[row] & 0xFFFFFFFFull);

    float4 xv = ((const float4*)(x   + (size_t)row * DDIM))[lane];
    float4 ev = ((const float4*)(emb + (size_t)bi  * DDIM))[lane];
    float4 q;
    q.x = xv.x + (ev.x - xv.x);
    q.y = xv.y + (ev.y - xv.y);
    q.z = xv.z + (ev.z - xv.z);
    q.w = xv.w + (ev.w - xv.w);
    ((float4*)(out_q + (size_t)row * DDIM))[lane] = q;

    float de = (ev.x - xv.x) * (ev.x - xv.x) + (ev.y - xv.y) * (ev.y - xv.y)
             + (ev.z - xv.z) * (ev.z - xv.z) + (ev.w - xv.w) * (ev.w - xv.w);
    float dq = (q.x - ev.x) * (q.x - ev.x) + (q.y - ev.y) * (q.y - ev.y)
             + (q.z - ev.z) * (q.z - ev.z) + (q.w - ev.w) * (q.w - ev.w);
    #pragma unroll
    for (int m = 32; m; m >>= 1) {
        de += __shfl_xor(de, m, 64);
        dq += __shfl_xor(dq, m, 64);
    }
    if (lane == 0) {
        out_idx[row] = (float)bi;
        atomicAdd(&counts[bi], 1);
        rde[wv] = de; rdq[wv] = dq;
    }
    __syncthreads();
    if (threadIdx.x == 0) {
        parts[blockIdx.x]        = rde[0] + rde[1] + rde[2] + rde[3];
        parts[4096 + blockIdx.x] = rdq[0] + rdq[1] + rdq[2] + rdq[3];
    }
}

__global__ __launch_bounds__(256) void scalars_kernel(
    const int* __restrict__ counts, const float* __restrict__ parts,
    float* __restrict__ out_loss, float* __restrict__ out_perp) {
    __shared__ float red[256], rde[256], rdq[256];
    float local = 0.0f, de = 0.0f, dq = 0.0f;
    for (int k = threadIdx.x; k < KCODES; k += 256) {
        float p = (float)counts[k] * (1.0f / (float)ND_ROWS);
        local += p * logf(p + 1e-10f);
    }
    for (int k = threadIdx.x; k < 4096; k += 256) {
        de += parts[k];
        dq += parts[4096 + k];
    }
    red[threadIdx.x] = local; rde[threadIdx.x] = de; rdq[threadIdx.x] = dq;
    __syncthreads();
    for (int s = 128; s; s >>= 1) {
        if (threadIdx.x < s) {
            red[threadIdx.x] += red[threadIdx.x + s];
            rde[threadIdx.x] += rde[threadIdx.x + s];
            rdq[threadIdx.x] += rdq[threadIdx.x + s];
        }
        __syncthreads();
    }
    if (threadIdx.x == 0) {
        *out_perp = expf(-red[0]);
        float invn = 1.0f / (float)(ND_ROWS * DDIM);
        *out_loss = rdq[0] * invn + 0.25f * (rde[0] * invn);
    }
}

extern "C" void kernel_launch(void* const* d_in, const int* in_sizes, int n_in,
                              void* d_out, int out_size, void* d_ws, size_t ws_size,
                              hipStream_t stream) {
    const float* x   = (const float*)d_in[0];
    const float* emb = (const float*)d_in[1];

    char* ws = (char*)d_ws;
    unsigned long long* minpair = (unsigned long long*)ws;         // 128 KB
    int*      counts = (int*)(ws + 131072);                        // 32 KB
    float*    parts  = (float*)(ws + 163840);                      // 32 KB
    float*    neF    = (float*)(ws + 196608);                      // 32 KB
    _Float16* Xp     = (_Float16*)(ws + 229376);                   // 16.8 MB
    _Float16* Bp     = (_Float16*)(ws + 17006592);                 // 8.4 MB

    float* out_q    = (float*)d_out;
    float* out_idx  = out_q + (size_t)ND_ROWS * DDIM;
    float* out_loss = out_idx + ND_ROWS;
    float* out_perp = out_loss + 1;

    hipMemsetAsync(minpair, 0xFF, ND_ROWS * sizeof(unsigned long long), stream);
    hipMemsetAsync(counts, 0, KCODES * sizeof(int), stream);

    prep_kernel<<<(KCODES + ND_ROWS) / 4, 256, 0, stream>>>(x, emb, Xp, Bp, neF);
    argmin_seg<<<NRG * NSEG, 512, 0, stream>>>(Xp, Bp, neF, minpair);
    finalize_kernel<<<ND_ROWS / 4, 256, 0, stream>>>(x, emb, minpair,
                                                     out_q, out_idx, counts, parts);
    scalars_kernel<<<1, 256, 0, stream>>>(counts, parts, out_loss, out_perp);
}